// Round 2
// baseline (1508.962 us; speedup 1.0000x reference)
//
#include <hip/hip_runtime.h>
#include <hip/hip_fp16.h>

// Problem: B=256, T=512, F=64, H=128  (GRU-D / BRITS-style recurrence)
// d_out (fp32): [0]=loss, [1..256]=predictions, [257..]=imputations [B,T,F]

#define NBATCH 256
#define NT 512
#define NF 64
#define NH 128

// ---- workspace byte offsets (16B aligned) ----
#define AFRAG_OFF 0u           // [256 tiles][64 lanes] uint4: MFMA A-frags of [W_ih|W_hh]
#define WHR_OFF   262144u      // [16][64]  uint4 packed f16 chunks of W_hr   ([k4][f])
#define WFR_OFF   278528u      // [8][64]   uint4 packed f16 chunks of W_fr (diag zeroed)
#define INVMS_OFF 286720u      // f32[512]
#define ISTR_OFF  288768u      // f32[1]
#define GH_OFF    294912u      // f16 [B*T*128] gamma_h
#define AL_OFF    33849344u    // f16 [B*T*64]  alpha

typedef _Float16 half2_t __attribute__((ext_vector_type(2)));
typedef _Float16 half8_t __attribute__((ext_vector_type(8)));
typedef float float4_t __attribute__((ext_vector_type(4)));

__device__ __forceinline__ unsigned pack2(float a, float b) {
    __half2 h = __floats2half2_rn(a, b);
    return __builtin_bit_cast(unsigned, h);
}

__device__ __forceinline__ float dot2f(unsigned w, unsigned a, float acc) {
#if __has_builtin(__builtin_amdgcn_fdot2)
    return __builtin_amdgcn_fdot2(__builtin_bit_cast(half2_t, w),
                                  __builtin_bit_cast(half2_t, a), acc, false);
#else
    float2 wf = __half22float2(__builtin_bit_cast(__half2, w));
    float2 af = __half22float2(__builtin_bit_cast(__half2, a));
    return acc + wf.x * af.x + wf.y * af.y;
#endif
}

__device__ __forceinline__ float4_t mfma16(half8_t a, half8_t b, float4_t c) {
    return __builtin_amdgcn_mfma_f32_16x16x32_f16(a, b, c, 0, 0, 0);
}

__device__ __forceinline__ float sigm(float x) { return 1.f / (1.f + __expf(-x)); }
__device__ __forceinline__ float tanh_fast(float x) { return 1.f - 2.f / (__expf(2.f * x) + 1.f); }

// ---------------------------------------------------------------------------
// prep_w: build (a) MFMA A-fragments for G = [W_ih | W_hh]  (512 rows x 256 k,
// k = [c_c(64), m(64), h(128)]), per-lane packed so main kernel loads are
// coalesced uint4; (b) W_hr / W_fr(zero-diag) f16x2 chunk layouts [k4][f].
// ---------------------------------------------------------------------------
__global__ __launch_bounds__(256) void prep_w(const float* __restrict__ Wih,
                                              const float* __restrict__ Whh,
                                              const float* __restrict__ Whr,
                                              const float* __restrict__ Wfr,
                                              unsigned* __restrict__ wsu) {
    int o = blockIdx.x * 256 + threadIdx.x;
    float v0, v1;
    if (o < 65536) {                      // A-fragments
        int comp = o & 3;
        int u4 = o >> 2;
        int lane = u4 & 63;
        int tile = u4 >> 6;               // = (w*4+rt)*8 + kt
        int kt = tile & 7, rt = (tile >> 3) & 3, w = tile >> 5;
        int row = 64 * w + 16 * rt + (lane & 15);
        int kp = 16 * kt + ((lane >> 4) << 2) + comp;   // u32-pair index
        int k0 = 2 * kp;
        if (k0 < 128) { v0 = Wih[row * 128 + k0]; v1 = Wih[row * 128 + k0 + 1]; }
        else          { v0 = Whh[row * 128 + k0 - 128]; v1 = Whh[row * 128 + k0 - 127]; }
    } else if (o < 69632) {               // W_hr [64][128] -> [k4][f]
        int o3 = o - 65536;
        int c = o3 & 3, f = (o3 >> 2) & 63, cb = o3 >> 8;
        int col = 8 * cb + 2 * c;
        v0 = Whr[f * 128 + col]; v1 = Whr[f * 128 + col + 1];
    } else if (o < 71680) {               // W_fr [64][64], zero diagonal
        int o4 = o - 69632;
        int c = o4 & 3, f = (o4 >> 2) & 63, cb = o4 >> 8;
        int col = 8 * cb + 2 * c;
        v0 = (col == f) ? 0.f : Wfr[f * 64 + col];
        v1 = (col + 1 == f) ? 0.f : Wfr[f * 64 + col + 1];
    } else {
        return;
    }
    wsu[o] = pack2(v0, v1);
}

// ---------------------------------------------------------------------------
// prep_msum: invms[t] = 1/(sum_b,f masks[b,t,f] + 1e-5); block 512:
// inv_istr = 1/(sum is_train + 1e-5), zero d_out[0].
// ---------------------------------------------------------------------------
__global__ __launch_bounds__(256) void prep_msum(const float* __restrict__ masks,
                                                 const float* __restrict__ is_train,
                                                 float* __restrict__ invms,
                                                 float* __restrict__ inv_istr,
                                                 float* __restrict__ d_out0) {
    __shared__ float red[256];
    int tid = threadIdx.x;
    int t = blockIdx.x;
    if (t < NT) {
        int f = tid & 63, br = tid >> 6;
        float s = 0.f;
        for (int i = 0; i < 64; i++) {
            int b = br + i * 4;
            s += masks[((size_t)b * NT + t) * NF + f];
        }
        red[tid] = s;
        __syncthreads();
        for (int off = 128; off > 0; off >>= 1) {
            if (tid < off) red[tid] += red[tid + off];
            __syncthreads();
        }
        if (tid == 0) invms[t] = 1.f / (red[0] + 1e-5f);
    } else {
        red[tid] = is_train[tid];
        __syncthreads();
        for (int off = 128; off > 0; off >>= 1) {
            if (tid < off) red[tid] += red[tid + off];
            __syncthreads();
        }
        if (tid == 0) {
            *inv_istr = 1.f / (red[0] + 1e-5f);
            *d_out0 = 0.f;
        }
    }
}

// ---------------------------------------------------------------------------
// ga_kernel: precompute gamma_h[b,t,128] and alpha[b,t,64] (f16).
// grid 16384 x 256, 8 (b,t) pairs per block.
// ---------------------------------------------------------------------------
__global__ __launch_bounds__(256) void ga_kernel(const float* __restrict__ deltas,
                                                 const float* __restrict__ masks,
                                                 const float* __restrict__ Wdh,
                                                 const float* __restrict__ bdh,
                                                 const float* __restrict__ Wdx,
                                                 const float* __restrict__ bdx,
                                                 const float* __restrict__ Wwc,
                                                 const float* __restrict__ bwc,
                                                 __half* __restrict__ gh_all,
                                                 __half* __restrict__ al_all) {
    __shared__ unsigned wdhpk[32 * 128];   // [k2][j]
    __shared__ unsigned wwcpk[64 * 64];    // [k2][f]
    __shared__ float sbdh[128], sbdx[64], swdx[64], sbwc[64];
    __shared__ float dbuf[64];
    __shared__ __align__(16) unsigned dpk[32], gxpk[32], mpk2[32];
    int tid = threadIdx.x;

    for (int o = tid; o < 4096; o += 256) {
        int j = o & 127, k2 = o >> 7;
        wdhpk[o] = pack2(Wdh[j * 64 + 2 * k2], Wdh[j * 64 + 2 * k2 + 1]);
    }
    for (int o = tid; o < 4096; o += 256) {
        int f = o & 63, k2 = o >> 6;
        wwcpk[o] = pack2(Wwc[f * 128 + 2 * k2], Wwc[f * 128 + 2 * k2 + 1]);
    }
    if (tid < 128) sbdh[tid] = bdh[tid];
    if (tid < 64) {
        sbdx[tid] = bdx[tid];
        swdx[tid] = Wdx[tid * 65];
        sbwc[tid] = bwc[tid];
    }
    __syncthreads();

    for (int i = 0; i < 8; i++) {
        int p = blockIdx.x * 8 + i;            // p = b*T + t
        if (tid < 32) {
            float2 dv = ((const float2*)(deltas + (size_t)p * NF))[tid];
            dbuf[2 * tid] = dv.x; dbuf[2 * tid + 1] = dv.y;
            dpk[tid] = pack2(dv.x, dv.y);
        } else if (tid < 64) {
            int q = tid - 32;
            float2 mv = ((const float2*)(masks + (size_t)p * NF))[q];
            mpk2[q] = pack2(mv.x, mv.y);
        }
        __syncthreads();
        if (tid < 64) {
            float gx = __expf(-fmaxf(dbuf[tid] * swdx[tid] + sbdx[tid], 0.f));
            float oth = __shfl_xor(gx, 1);
            if (!(tid & 1)) gxpk[tid >> 1] = pack2(gx, oth);
        }
        __syncthreads();
        if (tid < 128) {
            float a0 = sbdh[tid], a1 = 0.f;
            #pragma unroll
            for (int k8 = 0; k8 < 8; k8++) {
                uint4 dp = *(const uint4*)&dpk[4 * k8];
                a0 = dot2f(wdhpk[(4 * k8 + 0) * 128 + tid], dp.x, a0);
                a1 = dot2f(wdhpk[(4 * k8 + 1) * 128 + tid], dp.y, a1);
                a0 = dot2f(wdhpk[(4 * k8 + 2) * 128 + tid], dp.z, a0);
                a1 = dot2f(wdhpk[(4 * k8 + 3) * 128 + tid], dp.w, a1);
            }
            gh_all[(size_t)p * NH + tid] = __float2half(__expf(-fmaxf(a0 + a1, 0.f)));
        } else if (tid < 192) {
            int f = tid - 128;
            float a0 = sbwc[f], a1 = 0.f;
            #pragma unroll
            for (int k8 = 0; k8 < 8; k8++) {
                uint4 gp = *(const uint4*)&gxpk[4 * k8];
                a0 = dot2f(wwcpk[(4 * k8 + 0) * 64 + f], gp.x, a0);
                a1 = dot2f(wwcpk[(4 * k8 + 1) * 64 + f], gp.y, a1);
                a0 = dot2f(wwcpk[(4 * k8 + 2) * 64 + f], gp.z, a0);
                a1 = dot2f(wwcpk[(4 * k8 + 3) * 64 + f], gp.w, a1);
            }
            #pragma unroll
            for (int k8 = 0; k8 < 8; k8++) {
                uint4 mp = *(const uint4*)&mpk2[4 * k8];
                a0 = dot2f(wwcpk[(32 + 4 * k8 + 0) * 64 + f], mp.x, a0);
                a1 = dot2f(wwcpk[(32 + 4 * k8 + 1) * 64 + f], mp.y, a1);
                a0 = dot2f(wwcpk[(32 + 4 * k8 + 2) * 64 + f], mp.z, a0);
                a1 = dot2f(wwcpk[(32 + 4 * k8 + 3) * 64 + f], mp.w, a1);
            }
            al_all[(size_t)p * NF + f] = __float2half(a0 + a1);
        }
        __syncthreads();
    }
}

// ---------------------------------------------------------------------------
// main_kernel: one block per batch element, 512 threads (8 waves).
// Gates matvec via MFMA 16x16x32_f16; wave w owns gate rows [64w, 64w+64).
// A-fragments (the 512x256 weight matrix) live in pinned registers.
// ---------------------------------------------------------------------------
__global__ __launch_bounds__(512, 2) void main_kernel(
    const float* __restrict__ values, const float* __restrict__ masks,
    const float* __restrict__ labels, const float* __restrict__ is_train,
    const float* __restrict__ b_hr, const float* __restrict__ b_fr,
    const float* __restrict__ b_ih, const float* __restrict__ b_hh,
    const float* __restrict__ W_out, const float* __restrict__ b_out,
    const uint4* __restrict__ afrag_ws, const uint4* __restrict__ whr_ws,
    const uint4* __restrict__ wfr_ws,
    const float* __restrict__ invms, const float* __restrict__ inv_istr,
    const __half* __restrict__ gh_all, const __half* __restrict__ al_all,
    float* __restrict__ d_out) {
    __shared__ __align__(16) uint4 whr4u[16 * 64];   // 16 KB
    __shared__ __align__(16) uint4 wfr4u[8 * 64];    // 8 KB
    __shared__ float bpart[512], cpart[512], gates[512];
    __shared__ float xbuf[64], mbuf[64], albuf[64];
    __shared__ float sbhr[64], sbfr[64];
    __shared__ __align__(16) unsigned hpk[64];
    __shared__ __align__(16) unsigned mpk[32], xcpk[32], ccpk[32];
    __shared__ float sinv[1];

    const int tid = threadIdx.x;
    const int b = blockIdx.x;
    const int f = tid & 63;          // lane
    const int s = tid >> 6;          // wave
    const int q4 = (tid >> 4) & 3;   // lane>>4 within wave

    // ---- load & pin A-fragments (128 VGPRs of weights, loop-invariant) ----
    uint4 afr[4][8];
    #pragma unroll
    for (int rt = 0; rt < 4; rt++)
        #pragma unroll
        for (int kt = 0; kt < 8; kt++) {
            afr[rt][kt] = afrag_ws[(((s * 4 + rt) * 8) + kt) * 64 + f];
            asm volatile("" : "+v"(afr[rt][kt].x), "+v"(afr[rt][kt].y),
                              "+v"(afr[rt][kt].z), "+v"(afr[rt][kt].w));
        }

    // gate biases in C/D-layout registers
    float4_t bias_r[4];
    #pragma unroll
    for (int rt = 0; rt < 4; rt++)
        #pragma unroll
        for (int reg = 0; reg < 4; reg++) {
            int row = 64 * s + 16 * rt + 4 * q4 + reg;
            bias_r[rt][reg] = b_ih[row] + b_hh[row];
        }

    for (int o = tid; o < 1024; o += 512) whr4u[o] = whr_ws[o];
    if (tid < 512) wfr4u[tid] = wfr_ws[tid];
    if (tid < 64) { sbhr[tid] = b_hr[tid]; sbfr[tid] = b_fr[tid]; }

    const float* vp = values + (size_t)b * NT * NF;
    const float* mp = masks + (size_t)b * NT * NF;
    const __half* alp = al_all + (size_t)b * NT * NF;
    const __half* ghp = gh_all + (size_t)b * NT * NH;
    float* imp = d_out + 257 + (size_t)b * NT * NF;

    // ---- initial state / t=0 commits ----
    if (tid < 64) {
        float x0 = vp[tid];
        float m0 = mp[tid];
        xbuf[tid] = x0; mbuf[tid] = m0;
        albuf[tid] = __half2float(alp[tid]);
        float m1 = __shfl_xor(m0, 1);
        if (!(tid & 1)) mpk[tid >> 1] = pack2(m0, m1);
        hpk[tid] = 0u;
    }
    if (tid == 64) sinv[0] = invms[0];
    __syncthreads();

    float creg = 0.f, hn = 0.f;          // per-element LSTM state (tid<128)
    float lloss = 0.f;                   // per-thread loss partial (tid<64)

    for (int t = 0; t < NT; t++) {
        // ---- prefetch inputs for t+1 (committed in update phase) ----
        int tn = (t + 1 < NT) ? (t + 1) : (NT - 1);
        __half ghn = __float2half(0.f);
        float2 mn2 = make_float2(0.f, 0.f);
        float xn = 0.f, aln = 0.f, invtn = 0.f;
        if (tid < 128) ghn = ghp[(size_t)tn * NH + tid];
        else if (tid < 160) mn2 = ((const float2*)(mp + tn * NF))[tid - 128];
        else if (tid < 256 && tid >= 192) xn = vp[tn * NF + (tid - 192)];
        else if (tid >= 256 && tid < 320) aln = __half2float(alp[tn * NF + (tid - 256)]);
        else if (tid == 320) invtn = invms[tn];

        // ---- D-h: issue h-part MFMAs (overlaps B/C on the VALU) ----
        float4_t acc[4];
        {
            half8_t bh[4];
            #pragma unroll
            for (int j = 0; j < 4; j++)
                bh[j] = *((const half8_t*)&hpk[16 * j + 4 * q4]);
            #pragma unroll
            for (int rt = 0; rt < 4; rt++) {
                acc[rt] = bias_r[rt];
                #pragma unroll
                for (int j = 0; j < 4; j++)
                    acc[rt] = mfma16(__builtin_bit_cast(half8_t, afr[rt][4 + j]), bh[j], acc[rt]);
            }
        }

        // ---- B-dots: x_h partials, wave s covers k in [16s,16s+16) ----
        {
            uint4 w0 = whr4u[(2 * s) * 64 + f];
            uint4 w1 = whr4u[(2 * s + 1) * 64 + f];
            uint4 h0 = *(const uint4*)&hpk[8 * s];
            uint4 h1 = *(const uint4*)&hpk[8 * s + 4];
            float p0 = 0.f, p1 = 0.f;
            p0 = dot2f(w0.x, h0.x, p0); p1 = dot2f(w0.y, h0.y, p1);
            p0 = dot2f(w0.z, h0.z, p0); p1 = dot2f(w0.w, h0.w, p1);
            p0 = dot2f(w1.x, h1.x, p0); p1 = dot2f(w1.y, h1.y, p1);
            p0 = dot2f(w1.z, h1.z, p0); p1 = dot2f(w1.w, h1.w, p1);
            bpart[s * 64 + f] = p0 + p1;
        }
        __syncthreads();

        // ---- B-red: x_h, x_c, pack (tid<64) ----
        float xreg = 0.f, mreg = 0.f, invt = 0.f, xh_keep = 0.f;
        if (tid < 64) {
            float xh = sbhr[f];
            #pragma unroll
            for (int s2 = 0; s2 < 8; s2++) xh += bpart[s2 * 64 + f];
            xreg = xbuf[f]; mreg = mbuf[f]; invt = sinv[0];
            xh_keep = xh;
            float xc = mreg * xreg + (1.f - mreg) * xh;
            lloss += fabsf(xreg - xh) * mreg * invt;
            float oth = __shfl_xor(xc, 1);
            if (!(f & 1)) xcpk[f >> 1] = pack2(xc, oth);
        }
        __syncthreads();

        // ---- C-dots: z_h partials, wave s covers k in [8s,8s+8) ----
        {
            uint4 w = wfr4u[s * 64 + f];
            uint4 xp = *(const uint4*)&xcpk[4 * s];
            float p0 = 0.f, p1 = 0.f;
            p0 = dot2f(w.x, xp.x, p0); p1 = dot2f(w.y, xp.y, p1);
            p0 = dot2f(w.z, xp.z, p0); p1 = dot2f(w.w, xp.w, p1);
            cpart[s * 64 + f] = p0 + p1;
        }
        __syncthreads();

        // ---- C-red: z_h, c_h, c_c, imputation, loss, pack (tid<64) ----
        if (tid < 64) {
            float zh = sbfr[f];
            #pragma unroll
            for (int s2 = 0; s2 < 8; s2++) zh += cpart[s2 * 64 + f];
            float al = albuf[f];
            float ch = al * zh + (1.f - al) * xh_keep;
            float cc = mreg * xreg + (1.f - mreg) * ch;
            imp[t * NF + f] = cc;
            lloss += (fabsf(xreg - zh) + fabsf(xreg - ch)) * mreg * invt;
            float oth = __shfl_xor(cc, 1);
            if (!(f & 1)) ccpk[f >> 1] = pack2(cc, oth);
        }
        __syncthreads();

        // ---- D-ccm: remaining MFMAs + gate write ----
        {
            half8_t bc[4];
            bc[0] = *((const half8_t*)&ccpk[4 * q4]);
            bc[1] = *((const half8_t*)&ccpk[16 + 4 * q4]);
            bc[2] = *((const half8_t*)&mpk[4 * q4]);
            bc[3] = *((const half8_t*)&mpk[16 + 4 * q4]);
            #pragma unroll
            for (int rt = 0; rt < 4; rt++) {
                #pragma unroll
                for (int j = 0; j < 4; j++)
                    acc[rt] = mfma16(__builtin_bit_cast(half8_t, afr[rt][j]), bc[j], acc[rt]);
            }
            if ((tid & 15) == 0) {
                #pragma unroll
                for (int rt = 0; rt < 4; rt++)
                    *((float4_t*)&gates[64 * s + 16 * rt + 4 * q4]) = acc[rt];
            }
        }
        __syncthreads();

        // ---- update: LSTM pointwise + next-step gamma decay + commits ----
        if (tid < 128) {
            float gi = gates[tid], gf = gates[128 + tid];
            float gg = gates[256 + tid], go = gates[384 + tid];
            float cn = sigm(gf) * creg + sigm(gi) * tanh_fast(gg);
            creg = cn;
            hn = sigm(go) * tanh_fast(cn);
            float hd = hn * __half2float(ghn);     // decayed h for step t+1
            float oth = __shfl_xor(hd, 1);
            if (!(tid & 1)) hpk[tid >> 1] = pack2(hd, oth);
        } else if (tid < 160) {
            int q = tid - 128;
            mbuf[2 * q] = mn2.x; mbuf[2 * q + 1] = mn2.y;
            mpk[q] = pack2(mn2.x, mn2.y);
        } else if (tid >= 192 && tid < 256) {
            xbuf[tid - 192] = xn;
        } else if (tid >= 256 && tid < 320) {
            albuf[tid - 256] = aln;
        } else if (tid == 320) {
            sinv[0] = invtn;
        }
        __syncthreads();
    }

    // ---- finale: y_h, prediction, loss ----
    if (tid < 128) bpart[tid] = hn * W_out[tid];
    __syncthreads();
    if (tid < 64) {
        float yp = bpart[tid] + bpart[tid + 64];
        float ll = lloss;
        #pragma unroll
        for (int off = 32; off > 0; off >>= 1) {
            ll += __shfl_down(ll, off);
            yp += __shfl_down(yp, off);
        }
        if (tid == 0) {
            float yh = yp + b_out[0];
            d_out[1 + b] = 1.f / (1.f + expf(-yh));
            float lab = labels[b], istr = is_train[b];
            float maxv = fmaxf(-yh, 0.f);
            float yl = yh - yh * lab + maxv + logf(expf(-maxv) + expf(-yh - maxv));
            atomicAdd(d_out, ll * (1.f / (float)NT) + 0.3f * yl * istr * (*inv_istr));
        }
    }
}

// ---------------------------------------------------------------------------
extern "C" void kernel_launch(void* const* d_in, const int* in_sizes, int n_in,
                              void* d_out, int out_size, void* d_ws, size_t ws_size,
                              hipStream_t stream) {
    const float* values = (const float*)d_in[0];
    const float* masks = (const float*)d_in[1];
    const float* deltas = (const float*)d_in[2];
    const float* labels = (const float*)d_in[3];
    const float* is_train = (const float*)d_in[4];
    const float* W_dh = (const float*)d_in[5];
    const float* b_dh = (const float*)d_in[6];
    const float* W_dx = (const float*)d_in[7];
    const float* b_dx = (const float*)d_in[8];
    const float* W_hr = (const float*)d_in[9];
    const float* b_hr = (const float*)d_in[10];
    const float* W_fr = (const float*)d_in[11];
    const float* b_fr = (const float*)d_in[12];
    const float* W_wc = (const float*)d_in[13];
    const float* b_wc = (const float*)d_in[14];
    const float* W_ih = (const float*)d_in[15];
    const float* b_ih = (const float*)d_in[16];
    const float* W_hh = (const float*)d_in[17];
    const float* b_hh = (const float*)d_in[18];
    const float* W_out = (const float*)d_in[19];
    const float* b_out = (const float*)d_in[20];

    char* ws = (char*)d_ws;
    unsigned* wsu = (unsigned*)d_ws;
    const uint4* afrag_ws = (const uint4*)(ws + AFRAG_OFF);
    const uint4* whr_ws = (const uint4*)(ws + WHR_OFF);
    const uint4* wfr_ws = (const uint4*)(ws + WFR_OFF);
    float* invms = (float*)(ws + INVMS_OFF);
    float* inv_istr = (float*)(ws + ISTR_OFF);
    __half* gh_all = (__half*)(ws + GH_OFF);
    __half* al_all = (__half*)(ws + AL_OFF);
    float* out_f = (float*)d_out;

    prep_w<<<280, 256, 0, stream>>>(W_ih, W_hh, W_hr, W_fr, wsu);
    prep_msum<<<513, 256, 0, stream>>>(masks, is_train, invms, inv_istr, out_f);
    ga_kernel<<<16384, 256, 0, stream>>>(deltas, masks, W_dh, b_dh, W_dx, b_dx,
                                         W_wc, b_wc, gh_all, al_all);
    main_kernel<<<NBATCH, 512, 0, stream>>>(values, masks, labels, is_train,
                                            b_hr, b_fr, b_ih, b_hh, W_out, b_out,
                                            afrag_ws, whr_ws, wfr_ws,
                                            invms, inv_istr, gh_all, al_all, out_f);
}